// Round 1
// baseline (585.778 us; speedup 1.0000x reference)
//
#include <hip/hip_runtime.h>
#include <cstddef>

// Shapes
constexpr int H  = 256;
constexpr int Bb = 128;
constexpr int T  = 2048;
constexpr int V  = 32000;
constexpr int SPLITS = 16;          // T-splits for attention pass
constexpr int TC = T / SPLITS;      // 128 timesteps per block

// ---------------------------------------------------------------------------
// K1: fused attention scores + unnormalized context partials (one pass over enc)
// grid (SPLITS, B), block 256. Thread tid owns feature h=tid.
// scores[b][t] = dot(enc[t,b,:],W_e) + dot(hidden[b,:],W_h) + attn_b
// ctx_part[b][chunk][h] = sum_{t in chunk} exp(scores[b][t]) * enc[t,b,h]
// ---------------------------------------------------------------------------
__global__ __launch_bounds__(256) void k_attn(
    const float* __restrict__ enc, const float* __restrict__ hidden,
    const float* __restrict__ attn_W, const float* __restrict__ attn_b,
    float* __restrict__ scores, float* __restrict__ ctx_part) {
  const int b = blockIdx.y, chunk = blockIdx.x, tid = threadIdx.x;
  const int lane = tid & 63, wave = tid >> 6;
  __shared__ float red[16];
  __shared__ float hb_sh;

  const float we = attn_W[H + tid];
  const float wh = attn_W[tid];
  const float hv = hidden[b * H + tid];

  // block-reduce dot(hidden, W_h)
  float p = wh * hv;
  #pragma unroll
  for (int off = 32; off; off >>= 1) p += __shfl_down(p, off);
  if (lane == 0) red[wave] = p;
  __syncthreads();
  if (tid == 0) hb_sh = red[0] + red[1] + red[2] + red[3] + attn_b[0];
  __syncthreads();
  const float hb = hb_sh;

  float acc = 0.f;
  const float* encb = enc + (size_t)chunk * TC * (Bb * H) + (size_t)b * H + tid;
  const int t0base = chunk * TC;

  for (int t = 0; t < TC; t += 4) {
    float e0 = encb[(size_t)(t + 0) * (Bb * H)];
    float e1 = encb[(size_t)(t + 1) * (Bb * H)];
    float e2 = encb[(size_t)(t + 2) * (Bb * H)];
    float e3 = encb[(size_t)(t + 3) * (Bb * H)];
    float p0 = e0 * we, p1 = e1 * we, p2 = e2 * we, p3 = e3 * we;
    #pragma unroll
    for (int off = 32; off; off >>= 1) {
      p0 += __shfl_down(p0, off);
      p1 += __shfl_down(p1, off);
      p2 += __shfl_down(p2, off);
      p3 += __shfl_down(p3, off);
    }
    __syncthreads();               // previous iteration's red[] reads done
    if (lane == 0) {
      red[wave * 4 + 0] = p0; red[wave * 4 + 1] = p1;
      red[wave * 4 + 2] = p2; red[wave * 4 + 3] = p3;
    }
    __syncthreads();
    float s0 = red[0] + red[4] + red[8]  + red[12] + hb;
    float s1 = red[1] + red[5] + red[9]  + red[13] + hb;
    float s2 = red[2] + red[6] + red[10] + red[14] + hb;
    float s3 = red[3] + red[7] + red[11] + red[15] + hb;
    float w0 = __expf(s0), w1 = __expf(s1), w2 = __expf(s2), w3 = __expf(s3);
    acc += w0 * e0 + w1 * e1 + w2 * e2 + w3 * e3;
    if (tid < 4) {
      float sv = (tid == 0) ? s0 : (tid == 1) ? s1 : (tid == 2) ? s2 : s3;
      scores[(size_t)b * T + t0base + t + tid] = sv;
    }
  }
  ctx_part[((size_t)b * SPLITS + chunk) * H + tid] = acc;
}

// ---------------------------------------------------------------------------
// K2: exact softmax over scores (per b), write attn_w output (B,T,1),
// combine ctx partials -> ctx output (1,B,H). grid B, block 256.
// ---------------------------------------------------------------------------
__global__ __launch_bounds__(256) void k_softmax_ctx(
    const float* __restrict__ scores, const float* __restrict__ ctx_part,
    float* __restrict__ attn_o, float* __restrict__ ctx_o) {
  const int b = blockIdx.x, tid = threadIdx.x;
  const int lane = tid & 63, wave = tid >> 6;
  __shared__ float red[4];
  __shared__ float m_sh, l_sh;

  const float* sb = scores + (size_t)b * T;
  float s[8];
  #pragma unroll
  for (int q = 0; q < 8; q++) s[q] = sb[tid + 256 * q];

  float mx = s[0];
  #pragma unroll
  for (int q = 1; q < 8; q++) mx = fmaxf(mx, s[q]);
  #pragma unroll
  for (int off = 32; off; off >>= 1) mx = fmaxf(mx, __shfl_down(mx, off));
  if (lane == 0) red[wave] = mx;
  __syncthreads();
  if (tid == 0) m_sh = fmaxf(fmaxf(red[0], red[1]), fmaxf(red[2], red[3]));
  __syncthreads();
  const float m = m_sh;

  float w[8];
  float ps = 0.f;
  #pragma unroll
  for (int q = 0; q < 8; q++) { w[q] = __expf(s[q] - m); ps += w[q]; }
  #pragma unroll
  for (int off = 32; off; off >>= 1) ps += __shfl_down(ps, off);
  __syncthreads();
  if (lane == 0) red[wave] = ps;
  __syncthreads();
  if (tid == 0) l_sh = red[0] + red[1] + red[2] + red[3];
  __syncthreads();
  const float inv = 1.f / l_sh;

  #pragma unroll
  for (int q = 0; q < 8; q++) attn_o[(size_t)b * T + tid + 256 * q] = w[q] * inv;

  // ctx = exp(-m)/l * sum of unnormalized partials
  float c = 0.f;
  #pragma unroll
  for (int si = 0; si < SPLITS; si++) c += ctx_part[((size_t)b * SPLITS + si) * H + tid];
  ctx_o[(size_t)b * H + tid] = c * __expf(-m) * inv;
}

// ---------------------------------------------------------------------------
// K3: emb lookup + comb linear + ReLU + GRU cell -> h_new. grid B, block 256.
// ---------------------------------------------------------------------------
__global__ __launch_bounds__(256) void k_comb_gru(
    const int* __restrict__ tokens, const float* __restrict__ hidden,
    const float* __restrict__ emb_table,
    const float* __restrict__ comb_W, const float* __restrict__ comb_b,
    const float* __restrict__ Wih, const float* __restrict__ Whh,
    const float* __restrict__ bih, const float* __restrict__ bhh,
    const float* __restrict__ ctx_o, float* __restrict__ hnew) {
  const int b = blockIdx.x, tid = threadIdx.x;
  __shared__ __align__(16) float x2[2 * H];
  __shared__ __align__(16) float hid[H];
  __shared__ __align__(16) float xs[H];

  const int tok = tokens[b];
  x2[tid]     = emb_table[(size_t)tok * H + tid];
  x2[H + tid] = ctx_o[(size_t)b * H + tid];
  hid[tid]    = hidden[(size_t)b * H + tid];
  __syncthreads();

  // comb: xh[tid] = relu(dot(x2, comb_W[tid,:]) + comb_b[tid])
  {
    const float4* wr = (const float4*)(comb_W + (size_t)tid * (2 * H));
    const float4* xr = (const float4*)x2;
    float a = 0.f;
    #pragma unroll 8
    for (int k = 0; k < (2 * H) / 4; k++) {
      float4 w = wr[k], x = xr[k];
      a += w.x * x.x + w.y * x.y + w.z * x.z + w.w * x.w;
    }
    a += comb_b[tid];
    xs[tid] = fmaxf(a, 0.f);
  }
  __syncthreads();

  auto dot256 = [](const float* __restrict__ row, const float* __restrict__ v) -> float {
    const float4* r4 = (const float4*)row;
    const float4* v4 = (const float4*)v;
    float a = 0.f;
    #pragma unroll 8
    for (int k = 0; k < H / 4; k++) {
      float4 w = r4[k], x = v4[k];
      a += w.x * x.x + w.y * x.y + w.z * x.z + w.w * x.w;
    }
    return a;
  };

  float gxr = dot256(Wih + (size_t)tid * H,             xs) + bih[tid];
  float gxz = dot256(Wih + (size_t)(tid + H) * H,       xs) + bih[tid + H];
  float gxn = dot256(Wih + (size_t)(tid + 2 * H) * H,   xs) + bih[tid + 2 * H];
  float ghr = dot256(Whh + (size_t)tid * H,             hid) + bhh[tid];
  float ghz = dot256(Whh + (size_t)(tid + H) * H,       hid) + bhh[tid + H];
  float ghn = dot256(Whh + (size_t)(tid + 2 * H) * H,   hid) + bhh[tid + 2 * H];

  float r = 1.f / (1.f + __expf(-(gxr + ghr)));
  float z = 1.f / (1.f + __expf(-(gxz + ghz)));
  float n = tanhf(gxn + r * ghn);
  hnew[(size_t)b * H + tid] = (1.f - z) * n + z * hid[tid];
}

// ---------------------------------------------------------------------------
// K4a: logits = h_new @ out_W^T + out_b. LDS-tiled fp32 GEMM.
// grid V/128 = 250 blocks, block 256. v-tile 128, b-tile 128 (all), 8x8/thread.
// ---------------------------------------------------------------------------
__global__ __launch_bounds__(256) void k_logits(
    const float* __restrict__ hnew, const float* __restrict__ out_W,
    const float* __restrict__ out_b, float* __restrict__ logits) {
  const int tid = threadIdx.x;
  const int v0 = blockIdx.x * 128;
  const int tx = tid & 15, ty = tid >> 4;
  __shared__ __align__(16) float lW[128][36];   // pad 36 -> 2-way max (free)
  __shared__ __align__(16) float lH[128][36];

  float acc[8][8];
  #pragma unroll
  for (int i = 0; i < 8; i++)
    #pragma unroll
    for (int j = 0; j < 8; j++) acc[i][j] = 0.f;

  for (int k0 = 0; k0 < H; k0 += 32) {
    #pragma unroll
    for (int q = 0; q < 4; q++) {
      int idx = q * 1024 + tid * 4;
      int r = idx >> 5, c = idx & 31;
      float4 wv = *(const float4*)(out_W + (size_t)(v0 + r) * H + k0 + c);
      *(float4*)(&lW[r][c]) = wv;
      float4 hv = *(const float4*)(hnew + (size_t)r * H + k0 + c);
      *(float4*)(&lH[r][c]) = hv;
    }
    __syncthreads();
    #pragma unroll 4
    for (int kk = 0; kk < 32; kk++) {
      float hreg[8], wreg[8];
      #pragma unroll
      for (int i = 0; i < 8; i++) hreg[i] = lH[ty + 16 * i][kk];
      #pragma unroll
      for (int j = 0; j < 8; j++) wreg[j] = lW[tx + 16 * j][kk];
      #pragma unroll
      for (int i = 0; i < 8; i++)
        #pragma unroll
        for (int j = 0; j < 8; j++)
          acc[i][j] = fmaf(hreg[i], wreg[j], acc[i][j]);
    }
    __syncthreads();
  }

  float bj[8];
  #pragma unroll
  for (int j = 0; j < 8; j++) bj[j] = out_b[v0 + tx + 16 * j];
  #pragma unroll
  for (int i = 0; i < 8; i++) {
    int b = ty + 16 * i;
    float* dst = logits + (size_t)b * V + v0 + tx;
    #pragma unroll
    for (int j = 0; j < 8; j++) dst[16 * j] = acc[i][j] + bj[j];
  }
}

// ---------------------------------------------------------------------------
// K4b: lse[b] = logsumexp_v(logits[b,:]). grid B, block 256. Online (m,l).
// ---------------------------------------------------------------------------
__global__ __launch_bounds__(256) void k_lse(
    const float* __restrict__ logits, float* __restrict__ lse) {
  const int b = blockIdx.x, tid = threadIdx.x;
  const int lane = tid & 63, wave = tid >> 6;
  __shared__ float mred[4], lred[4];
  const float* lb = logits + (size_t)b * V;
  float m = -1e30f, l = 0.f;
  for (int v = tid; v < V; v += 256) {
    float x = lb[v];
    float nm = fmaxf(m, x);
    l = l * __expf(m - nm) + __expf(x - nm);
    m = nm;
  }
  #pragma unroll
  for (int off = 32; off; off >>= 1) {
    float mo = __shfl_down(m, off), lo = __shfl_down(l, off);
    float nm = fmaxf(m, mo);
    l = l * __expf(m - nm) + lo * __expf(mo - nm);
    m = nm;
  }
  if (lane == 0) { mred[wave] = m; lred[wave] = l; }
  __syncthreads();
  if (tid == 0) {
    float M = mred[0], L = lred[0];
    #pragma unroll
    for (int w = 1; w < 4; w++) {
      float nm = fmaxf(M, mred[w]);
      L = L * __expf(M - nm) + lred[w] * __expf(mred[w] - nm);
      M = nm;
    }
    lse[b] = M + logf(L);
  }
}

// ---------------------------------------------------------------------------
// K4c: logp = logits - lse[b], in place. grid (V/256, B).
// ---------------------------------------------------------------------------
__global__ __launch_bounds__(256) void k_sub(
    float* __restrict__ logits, const float* __restrict__ lse) {
  const int v = blockIdx.x * 256 + threadIdx.x;
  const int b = blockIdx.y;
  logits[(size_t)b * V + v] -= lse[b];
}

// ---------------------------------------------------------------------------
extern "C" void kernel_launch(void* const* d_in, const int* in_sizes, int n_in,
                              void* d_out, int out_size, void* d_ws, size_t ws_size,
                              hipStream_t stream) {
  const int*   tokens = (const int*)d_in[0];
  const float* hidden = (const float*)d_in[1];
  const float* enc    = (const float*)d_in[2];
  const float* emb    = (const float*)d_in[3];
  const float* attn_W = (const float*)d_in[4];
  const float* attn_b = (const float*)d_in[5];
  const float* comb_W = (const float*)d_in[6];
  const float* comb_b = (const float*)d_in[7];
  const float* Wih    = (const float*)d_in[8];
  const float* Whh    = (const float*)d_in[9];
  const float* bih    = (const float*)d_in[10];
  const float* bhh    = (const float*)d_in[11];
  const float* out_W  = (const float*)d_in[12];
  const float* out_b  = (const float*)d_in[13];

  float* out    = (float*)d_out;
  float* logp   = out;                                   // 128*32000
  float* hnew   = out + (size_t)Bb * V;                  // +4,096,000 : (1,B,H)
  float* attn_o = hnew + (size_t)Bb * H;                 // +32,768    : (B,T,1)
  float* ctx_o  = attn_o + (size_t)Bb * T;               // +262,144   : (1,B,H)

  float* ws       = (float*)d_ws;
  float* scores   = ws;                                  // B*T
  float* ctx_part = ws + (size_t)Bb * T;                 // B*SPLITS*H
  float* lse      = ctx_part + (size_t)Bb * SPLITS * H;  // B

  k_attn<<<dim3(SPLITS, Bb), 256, 0, stream>>>(enc, hidden, attn_W, attn_b, scores, ctx_part);
  k_softmax_ctx<<<dim3(Bb), 256, 0, stream>>>(scores, ctx_part, attn_o, ctx_o);
  k_comb_gru<<<dim3(Bb), 256, 0, stream>>>(tokens, hidden, emb, comb_W, comb_b,
                                           Wih, Whh, bih, bhh, ctx_o, hnew);
  k_logits<<<dim3(V / 128), 256, 0, stream>>>(hnew, out_W, out_b, logp);
  k_lse<<<dim3(Bb), 256, 0, stream>>>(logp, lse);
  k_sub<<<dim3(V / 256, Bb), 256, 0, stream>>>(logp, lse);
}

// Round 2
// 508.512 us; speedup vs baseline: 1.1519x; 1.1519x over previous
//
#include <hip/hip_runtime.h>
#include <cstddef>

// Shapes
constexpr int H  = 256;
constexpr int Bb = 128;
constexpr int T  = 2048;
constexpr int V  = 32000;
constexpr int SPLITS = 16;          // T-chunks for attention pass
constexpr int TC = T / SPLITS;      // 128 timesteps per block (32 per wave)
constexpr int NPART = SPLITS * 4;   // 64 ctx partials per b (per wave)
constexpr int LSE_SPLIT = 4;
constexpr int VS = V / LSE_SPLIT;   // 8000

typedef __attribute__((ext_vector_type(8))) short short8;
typedef __attribute__((ext_vector_type(4))) float f32x4;

// round-to-nearest-even fp32 -> bf16 (inputs are finite)
__device__ __forceinline__ unsigned short bf1(float a) {
  unsigned u = __builtin_bit_cast(unsigned, a);
  return (unsigned short)((u + 0x7fffu + ((u >> 16) & 1u)) >> 16);
}
__device__ __forceinline__ unsigned bfpack2(float a, float b) {
  unsigned ua = __builtin_bit_cast(unsigned, a);
  unsigned ub = __builtin_bit_cast(unsigned, b);
  ua = (ua + 0x7fffu + ((ua >> 16) & 1u)) >> 16;
  ub = (ub + 0x7fffu + ((ub >> 16) & 1u)) & 0xffff0000u;
  return ua | ub;
}

// ---------------------------------------------------------------------------
// K1: fused scores + unnormalized ctx partials. One pass over enc (256 MB).
// grid (SPLITS, B), block 256 = 4 waves. Wave owns 32 consecutive t.
// Per t: 1 KB coalesced load, per-lane dot(4), 6x shfl_xor butterfly -> all
// lanes hold score, exp, fused acc. No barriers, no LDS in the hot loop.
// ---------------------------------------------------------------------------
__global__ __launch_bounds__(256) void k_attn(
    const float* __restrict__ enc, const float* __restrict__ hidden,
    const float* __restrict__ attn_W, const float* __restrict__ attn_b,
    float* __restrict__ scores, float* __restrict__ ctx_part) {
  const int b = blockIdx.y, chunk = blockIdx.x;
  const int tid = threadIdx.x, lane = tid & 63, wave = tid >> 6;

  const float4 we = *(const float4*)(attn_W + H + lane * 4);
  const float4 wh = *(const float4*)(attn_W + lane * 4);
  const float4 hv = *(const float4*)(hidden + (size_t)b * H + lane * 4);

  float hb = fmaf(wh.x, hv.x, fmaf(wh.y, hv.y, fmaf(wh.z, hv.z, wh.w * hv.w)));
  #pragma unroll
  for (int off = 1; off < 64; off <<= 1) hb += __shfl_xor(hb, off);
  hb += attn_b[0];

  const int t0 = chunk * TC + wave * 32;
  const float* base = enc + (size_t)t0 * (Bb * H) + (size_t)b * H + lane * 4;

  float4 acc = {0.f, 0.f, 0.f, 0.f};
  for (int i = 0; i < 32; i += 4) {
    float4 e0 = *(const float4*)(base + (size_t)(i + 0) * (Bb * H));
    float4 e1 = *(const float4*)(base + (size_t)(i + 1) * (Bb * H));
    float4 e2 = *(const float4*)(base + (size_t)(i + 2) * (Bb * H));
    float4 e3 = *(const float4*)(base + (size_t)(i + 3) * (Bb * H));

    float p0 = fmaf(e0.x, we.x, fmaf(e0.y, we.y, fmaf(e0.z, we.z, e0.w * we.w)));
    float p1 = fmaf(e1.x, we.x, fmaf(e1.y, we.y, fmaf(e1.z, we.z, e1.w * we.w)));
    float p2 = fmaf(e2.x, we.x, fmaf(e2.y, we.y, fmaf(e2.z, we.z, e2.w * we.w)));
    float p3 = fmaf(e3.x, we.x, fmaf(e3.y, we.y, fmaf(e3.z, we.z, e3.w * we.w)));
    #pragma unroll
    for (int off = 1; off < 64; off <<= 1) {
      p0 += __shfl_xor(p0, off);
      p1 += __shfl_xor(p1, off);
      p2 += __shfl_xor(p2, off);
      p3 += __shfl_xor(p3, off);
    }
    float s0 = p0 + hb, s1 = p1 + hb, s2 = p2 + hb, s3 = p3 + hb;
    float w0 = __expf(s0), w1 = __expf(s1), w2 = __expf(s2), w3 = __expf(s3);

    acc.x = fmaf(w0, e0.x, fmaf(w1, e1.x, fmaf(w2, e2.x, fmaf(w3, e3.x, acc.x))));
    acc.y = fmaf(w0, e0.y, fmaf(w1, e1.y, fmaf(w2, e2.y, fmaf(w3, e3.y, acc.y))));
    acc.z = fmaf(w0, e0.z, fmaf(w1, e1.z, fmaf(w2, e2.z, fmaf(w3, e3.z, acc.z))));
    acc.w = fmaf(w0, e0.w, fmaf(w1, e1.w, fmaf(w2, e2.w, fmaf(w3, e3.w, acc.w))));

    if (lane == 0) {
      float4 sv = {s0, s1, s2, s3};
      *(float4*)(scores + (size_t)b * T + t0 + i) = sv;
    }
  }
  float* cp = ctx_part + ((size_t)b * NPART + chunk * 4 + wave) * H + lane * 4;
  *(float4*)cp = acc;
}

// ---------------------------------------------------------------------------
// K2: exact softmax over scores (per b) -> attn_w output; combine ctx
// partials with exp(-m)/l scaling -> ctx output. grid B, block 256.
// ---------------------------------------------------------------------------
__global__ __launch_bounds__(256) void k_softmax_ctx(
    const float* __restrict__ scores, const float* __restrict__ ctx_part,
    float* __restrict__ attn_o, float* __restrict__ ctx_o) {
  const int b = blockIdx.x, tid = threadIdx.x;
  const int lane = tid & 63, wave = tid >> 6;
  __shared__ float red[4];
  __shared__ float m_sh, l_sh;

  const float* sb = scores + (size_t)b * T;
  float s[8];
  #pragma unroll
  for (int q = 0; q < 8; q++) s[q] = sb[tid + 256 * q];

  float mx = s[0];
  #pragma unroll
  for (int q = 1; q < 8; q++) mx = fmaxf(mx, s[q]);
  #pragma unroll
  for (int off = 1; off < 64; off <<= 1) mx = fmaxf(mx, __shfl_xor(mx, off));
  if (lane == 0) red[wave] = mx;
  __syncthreads();
  if (tid == 0) m_sh = fmaxf(fmaxf(red[0], red[1]), fmaxf(red[2], red[3]));
  __syncthreads();
  const float m = m_sh;

  float w[8];
  float ps = 0.f;
  #pragma unroll
  for (int q = 0; q < 8; q++) { w[q] = __expf(s[q] - m); ps += w[q]; }
  #pragma unroll
  for (int off = 1; off < 64; off <<= 1) ps += __shfl_xor(ps, off);
  __syncthreads();
  if (lane == 0) red[wave] = ps;
  __syncthreads();
  if (tid == 0) l_sh = red[0] + red[1] + red[2] + red[3];
  __syncthreads();
  const float inv = 1.f / l_sh;

  #pragma unroll
  for (int q = 0; q < 8; q++) attn_o[(size_t)b * T + tid + 256 * q] = w[q] * inv;

  float c = 0.f;
  for (int si = 0; si < NPART; si++)
    c += ctx_part[((size_t)b * NPART + si) * H + tid];
  ctx_o[(size_t)b * H + tid] = c * __expf(-m) * inv;
}

// ---------------------------------------------------------------------------
// K3: emb lookup + comb linear + ReLU + GRU cell -> h_new (fp32 out + bf16
// copy for the MFMA logits GEMM). grid B, block 256.
// ---------------------------------------------------------------------------
__global__ __launch_bounds__(256) void k_comb_gru(
    const int* __restrict__ tokens, const float* __restrict__ hidden,
    const float* __restrict__ emb_table,
    const float* __restrict__ comb_W, const float* __restrict__ comb_b,
    const float* __restrict__ Wih, const float* __restrict__ Whh,
    const float* __restrict__ bih, const float* __restrict__ bhh,
    const float* __restrict__ ctx_o, float* __restrict__ hnew,
    unsigned short* __restrict__ hnewb) {
  const int b = blockIdx.x, tid = threadIdx.x;
  __shared__ __align__(16) float x2[2 * H];
  __shared__ __align__(16) float hid[H];
  __shared__ __align__(16) float xs[H];

  const int tok = tokens[b];
  x2[tid]     = emb_table[(size_t)tok * H + tid];
  x2[H + tid] = ctx_o[(size_t)b * H + tid];
  hid[tid]    = hidden[(size_t)b * H + tid];
  __syncthreads();

  {
    const float4* wr = (const float4*)(comb_W + (size_t)tid * (2 * H));
    const float4* xr = (const float4*)x2;
    float a = 0.f;
    #pragma unroll 8
    for (int k = 0; k < (2 * H) / 4; k++) {
      float4 w = wr[k], x = xr[k];
      a += w.x * x.x + w.y * x.y + w.z * x.z + w.w * x.w;
    }
    a += comb_b[tid];
    xs[tid] = fmaxf(a, 0.f);
  }
  __syncthreads();

  auto dot256 = [](const float* __restrict__ row, const float* __restrict__ v) -> float {
    const float4* r4 = (const float4*)row;
    const float4* v4 = (const float4*)v;
    float a = 0.f;
    #pragma unroll 8
    for (int k = 0; k < H / 4; k++) {
      float4 w = r4[k], x = v4[k];
      a += w.x * x.x + w.y * x.y + w.z * x.z + w.w * x.w;
    }
    return a;
  };

  float gxr = dot256(Wih + (size_t)tid * H,           xs) + bih[tid];
  float gxz = dot256(Wih + (size_t)(tid + H) * H,     xs) + bih[tid + H];
  float gxn = dot256(Wih + (size_t)(tid + 2 * H) * H, xs) + bih[tid + 2 * H];
  float ghr = dot256(Whh + (size_t)tid * H,           hid) + bhh[tid];
  float ghz = dot256(Whh + (size_t)(tid + H) * H,     hid) + bhh[tid + H];
  float ghn = dot256(Whh + (size_t)(tid + 2 * H) * H, hid) + bhh[tid + 2 * H];

  float r = 1.f / (1.f + __expf(-(gxr + ghr)));
  float z = 1.f / (1.f + __expf(-(gxz + ghz)));
  float n = tanhf(gxn + r * ghn);
  float hv = (1.f - z) * n + z * hid[tid];
  hnew[(size_t)b * H + tid] = hv;
  hnewb[(size_t)b * H + tid] = bf1(hv);
}

// ---------------------------------------------------------------------------
// K4a: logits = h_new @ out_W^T + out_b via bf16 MFMA 16x16x32.
// grid 250, block 256 (4 waves). v-tile 128 (wave owns 32 cols), b = all 128.
// out_W converted fp32->bf16 (RNE) during LDS staging. Row stride 144 B:
// 16B-aligned, bank-balanced at the intrinsic 8-word b128 floor.
// Layouts (m89-verified): A[m=lane&15][k=quad*8+j]; C/D col=lane&15,
// row=quad*4+reg.
// ---------------------------------------------------------------------------
constexpr int LSTR = 72;   // shorts per LDS row (64 data + 8 pad) = 144 B
__global__ __launch_bounds__(256) void k_logits(
    const unsigned short* __restrict__ hnewb, const float* __restrict__ out_W,
    const float* __restrict__ out_b, float* __restrict__ logits) {
  const int tid = threadIdx.x;
  const int lane = tid & 63, wave = tid >> 6;
  const int v0 = blockIdx.x * 128;
  const int r16 = lane & 15, quad = lane >> 4;

  __shared__ __align__(16) short lA[128 * LSTR];
  __shared__ __align__(16) short lB[128 * LSTR];

  f32x4 acc[8][2];
  #pragma unroll
  for (int mt = 0; mt < 8; mt++) {
    acc[mt][0] = (f32x4){0.f, 0.f, 0.f, 0.f};
    acc[mt][1] = (f32x4){0.f, 0.f, 0.f, 0.f};
  }

  for (int k0 = 0; k0 < H; k0 += 64) {
    // stage A (already bf16): 128 rows x 64 shorts
    #pragma unroll
    for (int q = 0; q < 4; q++) {
      int idx = q * 256 + tid;            // 0..1023
      int row = idx >> 3, c8 = idx & 7;   // 8-short groups
      f32x4 v = *(const f32x4*)(hnewb + (size_t)row * H + k0 + c8 * 8);
      *(f32x4*)(&lA[row * LSTR + c8 * 8]) = v;
    }
    // stage B with fp32->bf16 convert: 128 rows x 64 floats
    #pragma unroll
    for (int q = 0; q < 8; q++) {
      int idx = q * 256 + tid;            // 0..2047
      int row = idx >> 4, c4 = idx & 15;  // float4 groups
      f32x4 wv = *(const f32x4*)(out_W + (size_t)(v0 + row) * H + k0 + c4 * 4);
      uint2 p;
      p.x = bfpack2(wv.x, wv.y);
      p.y = bfpack2(wv.z, wv.w);
      *(uint2*)(&lB[row * LSTR + c4 * 4]) = p;
    }
    __syncthreads();
    #pragma unroll
    for (int ks = 0; ks < 2; ks++) {
      short8 bf[2];
      #pragma unroll
      for (int nt = 0; nt < 2; nt++) {
        int row = wave * 32 + nt * 16 + r16;
        bf[nt] = *(const short8*)(&lB[row * LSTR + ks * 32 + quad * 8]);
      }
      #pragma unroll
      for (int mt = 0; mt < 8; mt++) {
        short8 af = *(const short8*)(&lA[(mt * 16 + r16) * LSTR + ks * 32 + quad * 8]);
        acc[mt][0] = __builtin_amdgcn_mfma_f32_16x16x32_bf16(af, bf[0], acc[mt][0], 0, 0, 0);
        acc[mt][1] = __builtin_amdgcn_mfma_f32_16x16x32_bf16(af, bf[1], acc[mt][1], 0, 0, 0);
      }
    }
    __syncthreads();
  }

  #pragma unroll
  for (int nt = 0; nt < 2; nt++) {
    int col = v0 + wave * 32 + nt * 16 + r16;
    float bias = out_b[col];
    #pragma unroll
    for (int mt = 0; mt < 8; mt++) {
      int brow = mt * 16 + quad * 4;
      #pragma unroll
      for (int r = 0; r < 4; r++)
        logits[(size_t)(brow + r) * V + col] = acc[mt][nt][r] + bias;
    }
  }
}

// ---------------------------------------------------------------------------
// K4b: partial logsumexp. grid (B, 4), block 256, float4 loads with 4
// independent online (m,l) chains. Partials -> ws.
// ---------------------------------------------------------------------------
__global__ __launch_bounds__(256) void k_lse(
    const float* __restrict__ logits, float2* __restrict__ lse_part) {
  const int b = blockIdx.x, s = blockIdx.y, tid = threadIdx.x;
  const int lane = tid & 63, wave = tid >> 6;
  const float4* base = (const float4*)(logits + (size_t)b * V + (size_t)s * VS);

  float4 m4 = {-1e30f, -1e30f, -1e30f, -1e30f};
  float4 l4 = {0.f, 0.f, 0.f, 0.f};
  for (int i = tid; i < VS / 4; i += 256) {
    float4 x = base[i];
    float nm;
    nm = fmaxf(m4.x, x.x); l4.x = l4.x * __expf(m4.x - nm) + __expf(x.x - nm); m4.x = nm;
    nm = fmaxf(m4.y, x.y); l4.y = l4.y * __expf(m4.y - nm) + __expf(x.y - nm); m4.y = nm;
    nm = fmaxf(m4.z, x.z); l4.z = l4.z * __expf(m4.z - nm) + __expf(x.z - nm); m4.z = nm;
    nm = fmaxf(m4.w, x.w); l4.w = l4.w * __expf(m4.w - nm) + __expf(x.w - nm); m4.w = nm;
  }
  float m = fmaxf(fmaxf(m4.x, m4.y), fmaxf(m4.z, m4.w));
  float l = l4.x * __expf(m4.x - m) + l4.y * __expf(m4.y - m) +
            l4.z * __expf(m4.z - m) + l4.w * __expf(m4.w - m);
  #pragma unroll
  for (int off = 1; off < 64; off <<= 1) {
    float mo = __shfl_xor(m, off), lo = __shfl_xor(l, off);
    float nm = fmaxf(m, mo);
    l = l * __expf(m - nm) + lo * __expf(mo - nm);
    m = nm;
  }
  __shared__ float sm[4], sl[4];
  if (lane == 0) { sm[wave] = m; sl[wave] = l; }
  __syncthreads();
  if (tid == 0) {
    float M = sm[0], L = sl[0];
    #pragma unroll
    for (int w2 = 1; w2 < 4; w2++) {
      float nm = fmaxf(M, sm[w2]);
      L = L * __expf(M - nm) + sl[w2] * __expf(sm[w2] - nm);
      M = nm;
    }
    lse_part[b * LSE_SPLIT + s] = make_float2(M, L);
  }
}

// ---------------------------------------------------------------------------
// K4c: logp = logits - lse (in place, float4). grid (32, B).
// ---------------------------------------------------------------------------
__global__ __launch_bounds__(256) void k_sub(
    float* __restrict__ logits, const float2* __restrict__ lse_part) {
  const int b = blockIdx.y;
  const int i = blockIdx.x * 256 + threadIdx.x;   // float4 index
  float2 p0 = lse_part[b * 4 + 0], p1 = lse_part[b * 4 + 1];
  float2 p2 = lse_part[b * 4 + 2], p3 = lse_part[b * 4 + 3];
  float M = fmaxf(fmaxf(p0.x, p1.x), fmaxf(p2.x, p3.x));
  float L = p0.y * __expf(p0.x - M) + p1.y * __expf(p1.x - M) +
            p2.y * __expf(p2.x - M) + p3.y * __expf(p3.x - M);
  float lse = M + logf(L);
  if (i < V / 4) {
    float4* p = (float4*)(logits + (size_t)b * V) + i;
    float4 x = *p;
    x.x -= lse; x.y -= lse; x.z -= lse; x.w -= lse;
    *p = x;
  }
}

// ---------------------------------------------------------------------------
extern "C" void kernel_launch(void* const* d_in, const int* in_sizes, int n_in,
                              void* d_out, int out_size, void* d_ws, size_t ws_size,
                              hipStream_t stream) {
  const int*   tokens = (const int*)d_in[0];
  const float* hidden = (const float*)d_in[1];
  const float* enc    = (const float*)d_in[2];
  const float* emb    = (const float*)d_in[3];
  const float* attn_W = (const float*)d_in[4];
  const float* attn_b = (const float*)d_in[5];
  const float* comb_W = (const float*)d_in[6];
  const float* comb_b = (const float*)d_in[7];
  const float* Wih    = (const float*)d_in[8];
  const float* Whh    = (const float*)d_in[9];
  const float* bih    = (const float*)d_in[10];
  const float* bhh    = (const float*)d_in[11];
  const float* out_W  = (const float*)d_in[12];
  const float* out_b  = (const float*)d_in[13];

  float* out    = (float*)d_out;
  float* logp   = out;                                   // (1,B,V)
  float* hnew   = out + (size_t)Bb * V;                  // (1,B,H)
  float* attn_o = hnew + (size_t)Bb * H;                 // (B,T,1)
  float* ctx_o  = attn_o + (size_t)Bb * T;               // (1,B,H)

  float* ws       = (float*)d_ws;
  float* scores   = ws;                                     // B*T
  float* ctx_part = ws + (size_t)Bb * T;                    // B*NPART*H
  float2* lse_part = (float2*)(ctx_part + (size_t)Bb * NPART * H);  // B*4 float2
  unsigned short* hnewb = (unsigned short*)(lse_part + Bb * LSE_SPLIT); // B*H bf16

  k_attn<<<dim3(SPLITS, Bb), 256, 0, stream>>>(enc, hidden, attn_W, attn_b, scores, ctx_part);
  k_softmax_ctx<<<dim3(Bb), 256, 0, stream>>>(scores, ctx_part, attn_o, ctx_o);
  k_comb_gru<<<dim3(Bb), 256, 0, stream>>>(tokens, hidden, emb, comb_W, comb_b,
                                           Wih, Whh, bih, bhh, ctx_o, hnew, hnewb);
  k_logits<<<dim3(V / 128), 256, 0, stream>>>(hnewb, out_W, out_b, logp);
  k_lse<<<dim3(Bb, LSE_SPLIT), 256, 0, stream>>>(logp, lse_part);
  k_sub<<<dim3(V / 1024 + 1, Bb), 256, 0, stream>>>(logp, lse_part);
}